// Round 21
// baseline (119.864 us; speedup 1.0000x reference)
//
#include <hip/hip_runtime.h>
#include <cstdint>
#include <cmath>

#define B_   8
#define L_   1024
#define DM_  256
#define DS_  16
#define DC_  4
#define DI_  512
#define DTR_ 16
#define M_   (B_*L_)    // 8192
#define NCH  64         // number of scan chunks
#define CH   16         // chunk length (NCH*CH == L_)

using half8 = __attribute__((ext_vector_type(8))) _Float16;
using half4 = __attribute__((ext_vector_type(4))) _Float16;
using f32x4 = __attribute__((ext_vector_type(4))) float;

// ---------------------------------------------------------------------------
// load 8 contiguous elements as fp16, converting from fp32 if F32
// ---------------------------------------------------------------------------
template<bool F32>
__device__ __forceinline__ half8 load_h8(const void* base, size_t off)
{
    if constexpr (F32) {
        const float* p = (const float*)base + off;
        const float4 a = *reinterpret_cast<const float4*>(p);
        const float4 b = *reinterpret_cast<const float4*>(p + 4);
        half8 h;
        h[0] = (_Float16)a.x; h[1] = (_Float16)a.y;
        h[2] = (_Float16)a.z; h[3] = (_Float16)a.w;
        h[4] = (_Float16)b.x; h[5] = (_Float16)b.y;
        h[6] = (_Float16)b.z; h[7] = (_Float16)b.w;
        return h;
    } else {
        return *reinterpret_cast<const half8*>((const _Float16*)base + off);
    }
}

// ---------------------------------------------------------------------------
// prep: all fp32->fp16 converts in ONE kernel.
// ---------------------------------------------------------------------------
__global__ __launch_bounds__(256)
void prep_k(const float* __restrict__ state, const float* __restrict__ ipw,
            const float* __restrict__ opw,
            const float* __restrict__ w1, const float* __restrict__ w2,
            _Float16* __restrict__ st_h, _Float16* __restrict__ wih,
            _Float16* __restrict__ woh,
            _Float16* __restrict__ w1t, _Float16* __restrict__ w2t)
{
    const int g = blockIdx.x * 256 + threadIdx.x;
    const int N0 = M_ * DM_ / 4;            // 524288
    const int N1 = N0 + 2 * DI_ * DM_ / 4;  // +65536
    const int N2 = N1 + DM_ * DI_ / 4;      // +32768
    const int N3 = N2 + 256 * 256;          // +65536 (scalar)
    const int N4 = N3 + 256 * 128;          // +32768 (scalar)
    if (g < N0) {
        const float4 v = reinterpret_cast<const float4*>(state)[g];
        half4 h; h[0]=(_Float16)v.x; h[1]=(_Float16)v.y; h[2]=(_Float16)v.z; h[3]=(_Float16)v.w;
        reinterpret_cast<half4*>(st_h)[g] = h;
    } else if (g < N1) {
        const int gg = g - N0;
        const float4 v = reinterpret_cast<const float4*>(ipw)[gg];
        half4 h; h[0]=(_Float16)v.x; h[1]=(_Float16)v.y; h[2]=(_Float16)v.z; h[3]=(_Float16)v.w;
        reinterpret_cast<half4*>(wih)[gg] = h;
    } else if (g < N2) {
        const int gg = g - N1;
        const float4 v = reinterpret_cast<const float4*>(opw)[gg];
        half4 h; h[0]=(_Float16)v.x; h[1]=(_Float16)v.y; h[2]=(_Float16)v.z; h[3]=(_Float16)v.w;
        reinterpret_cast<half4*>(woh)[gg] = h;
    } else if (g < N3) {
        const int gg = g - N2;
        const int r = gg >> 8, c = gg & 255;
        w1t[(size_t)c * 256 + r] = (_Float16)w1[gg];
    } else if (g < N4) {
        const int gg = g - N3;
        const int r = gg >> 7, c = gg & 127;
        w2t[(size_t)c * 256 + r] = (_Float16)w2[gg];
    }
}

// ---------------------------------------------------------------------------
// in_proj GEMM + fused causal conv/SiLU on the x side (R15, unchanged).
// ---------------------------------------------------------------------------
__global__ __launch_bounds__(256)
void inproj_k(const _Float16* __restrict__ A, const _Float16* __restrict__ W,
              const float* __restrict__ cw, const float* __restrict__ cb,
              _Float16* __restrict__ xs, _Float16* __restrict__ gout)
{
    __shared__ _Float16 Ash[144][72];
    __shared__ _Float16 Bsh[64][72];
    _Float16 (*xsh)[152] = reinterpret_cast<_Float16(*)[152]>(&Ash[0][0]);

    const int tid  = threadIdx.x;
    const int lane = tid & 63;
    const int w    = tid >> 6;
    const int wm   = (w >> 1) * 64;
    const int wn   = (w & 1) * 32;
    const int bm   = blockIdx.x * 128;
    const int bn   = blockIdx.y * 64;
    const bool xside = (bn < DI_);
    const bool first = ((bm & (L_ - 1)) == 0);

    const int fr = lane & 15;
    const int fk = (lane >> 4) * 8;
    const int sr = tid >> 2;
    const int sc = (tid & 3) * 16;

    f32x4 acc[4][2] = {};
    f32x4 hacc[2] = {};

    for (int k0 = 0; k0 < DM_; k0 += 64) {
        #pragma unroll
        for (int hh = 0; hh < 2; hh++) {
            const int c = sc + hh * 8;
            *reinterpret_cast<half8*>(&Ash[16 + sr][c]) =
                *reinterpret_cast<const half8*>(A + (size_t)(bm + sr) * DM_ + k0 + c);
            *reinterpret_cast<half8*>(&Ash[16 + sr + 64][c]) =
                *reinterpret_cast<const half8*>(A + (size_t)(bm + sr + 64) * DM_ + k0 + c);
            *reinterpret_cast<half8*>(&Bsh[sr][c]) =
                *reinterpret_cast<const half8*>(W + (size_t)(bn + sr) * DM_ + k0 + c);
            if (tid < 64) {
                half8 hv = half8{};
                if (xside && !first)
                    hv = *reinterpret_cast<const half8*>(
                        A + (size_t)(bm - 16 + sr) * DM_ + k0 + c);
                *reinterpret_cast<half8*>(&Ash[sr][c]) = hv;
            }
        }
        __syncthreads();

        #pragma unroll
        for (int kk = 0; kk < 64; kk += 32) {
            half8 af[4], bf[2];
            #pragma unroll
            for (int mf = 0; mf < 4; mf++)
                af[mf] = *reinterpret_cast<const half8*>(&Ash[16 + wm + mf * 16 + fr][kk + fk]);
            #pragma unroll
            for (int nf = 0; nf < 2; nf++)
                bf[nf] = *reinterpret_cast<const half8*>(&Bsh[wn + nf * 16 + fr][kk + fk]);
            #pragma unroll
            for (int mf = 0; mf < 4; mf++)
                #pragma unroll
                for (int nf = 0; nf < 2; nf++)
                    acc[mf][nf] = __builtin_amdgcn_mfma_f32_16x16x32_f16(
                        af[mf], bf[nf], acc[mf][nf], 0, 0, 0);
            if (xside && w < 2) {
                const half8 ha = *reinterpret_cast<const half8*>(&Ash[fr][kk + fk]);
                #pragma unroll
                for (int nf = 0; nf < 2; nf++)
                    hacc[nf] = __builtin_amdgcn_mfma_f32_16x16x32_f16(
                        ha, bf[nf], hacc[nf], 0, 0, 0);
            }
        }
        __syncthreads();
    }

    const int orow = (lane >> 4) * 4;
    const int ocol = lane & 15;

    if (!xside) {
        #pragma unroll
        for (int mf = 0; mf < 4; mf++) {
            #pragma unroll
            for (int nf = 0; nf < 2; nf++) {
                const int gc = bn + wn + nf * 16 + ocol - DI_;
                #pragma unroll
                for (int r = 0; r < 4; r++) {
                    const int gr = bm + wm + mf * 16 + orow + r;
                    const float v = acc[mf][nf][r];
                    const float g = v * (1.f / (1.f + __expf(-v)));
                    gout[(size_t)gr * DI_ + gc] = (_Float16)g;
                }
            }
        }
        return;
    }

    #pragma unroll
    for (int mf = 0; mf < 4; mf++) {
        #pragma unroll
        for (int nf = 0; nf < 2; nf++) {
            half4 hv;
            #pragma unroll
            for (int r = 0; r < 4; r++) hv[r] = (_Float16)acc[mf][nf][r];
            *reinterpret_cast<half4*>(
                &xsh[wn + nf * 16 + ocol][16 + wm + mf * 16 + orow]) = hv;
        }
    }
    if (w < 2) {
        #pragma unroll
        for (int nf = 0; nf < 2; nf++) {
            half4 hv;
            #pragma unroll
            for (int r = 0; r < 4; r++) hv[r] = (_Float16)hacc[nf][r];
            *reinterpret_cast<half4*>(&xsh[wn + nf * 16 + ocol][orow]) = hv;
        }
    }
    __syncthreads();

    const int cc = tid & 63;
    const int r0 = (tid >> 6) * 32;
    const int gc = bn + cc;
    const float cb0 = cb[gc];
    float cwv[DC_];
    #pragma unroll
    for (int k = 0; k < DC_; k++) cwv[k] = cw[gc * DC_ + k];

    float xw[36];
    #pragma unroll
    for (int q = 0; q < 9; q++) {
        const half4 hv = *reinterpret_cast<const half4*>(&xsh[cc][12 + r0 + 4 * q]);
        #pragma unroll
        for (int j = 0; j < 4; j++) xw[4 * q + j] = (float)hv[j];
    }
    #pragma unroll
    for (int i = 0; i < 32; i++) {
        float a = cb0;
        #pragma unroll
        for (int k = 0; k < DC_; k++)
            a += xw[1 + i + k] * cwv[k];
        const float s = a * (1.f / (1.f + __expf(-a)));
        xs[(size_t)(bm + r0 + i) * DI_ + gc] = (_Float16)s;
    }
}

// ---------------------------------------------------------------------------
// fp16 MFMA GEMM, tile 64x64, BK=64 (out_proj, mlp1).
// ---------------------------------------------------------------------------
template<int ACT, bool BIAS>
__global__ __launch_bounds__(256)
void hgemm64_k(const _Float16* __restrict__ A, int lda,
               const _Float16* __restrict__ W,
               const float* __restrict__ bias,
               _Float16* __restrict__ Cv, int ldc, int K)
{
    __shared__ _Float16 Ash[64][72];
    __shared__ _Float16 Bsh[64][72];
    const int tid  = threadIdx.x;
    const int lane = tid & 63;
    const int w    = tid >> 6;
    const int wm   = (w >> 1) * 32;
    const int wn   = (w & 1) * 32;
    const int bm   = blockIdx.x * 64;
    const int bn   = blockIdx.y * 64;

    const int fr = lane & 15;
    const int fk = (lane >> 4) * 8;
    const int sr = tid >> 2;
    const int sc = (tid & 3) * 16;

    f32x4 acc[2][2] = {};

    for (int k0 = 0; k0 < K; k0 += 64) {
        #pragma unroll
        for (int hh = 0; hh < 2; hh++) {
            const int c = sc + hh * 8;
            *reinterpret_cast<half8*>(&Ash[sr][c]) =
                *reinterpret_cast<const half8*>(A + (size_t)(bm + sr) * lda + k0 + c);
            *reinterpret_cast<half8*>(&Bsh[sr][c]) =
                *reinterpret_cast<const half8*>(W + (size_t)(bn + sr) * K + k0 + c);
        }
        __syncthreads();

        #pragma unroll
        for (int kk = 0; kk < 64; kk += 32) {
            half8 af[2], bf[2];
            #pragma unroll
            for (int mf = 0; mf < 2; mf++)
                af[mf] = *reinterpret_cast<const half8*>(&Ash[wm + mf * 16 + fr][kk + fk]);
            #pragma unroll
            for (int nf = 0; nf < 2; nf++)
                bf[nf] = *reinterpret_cast<const half8*>(&Bsh[wn + nf * 16 + fr][kk + fk]);
            #pragma unroll
            for (int mf = 0; mf < 2; mf++)
                #pragma unroll
                for (int nf = 0; nf < 2; nf++)
                    acc[mf][nf] = __builtin_amdgcn_mfma_f32_16x16x32_f16(
                        af[mf], bf[nf], acc[mf][nf], 0, 0, 0);
        }
        __syncthreads();
    }

    const int orow = (lane >> 4) * 4;
    const int ocol = lane & 15;
    #pragma unroll
    for (int mf = 0; mf < 2; mf++) {
        #pragma unroll
        for (int nf = 0; nf < 2; nf++) {
            const int gc = bn + wn + nf * 16 + ocol;
            float b = BIAS ? bias[gc] : 0.f;
            #pragma unroll
            for (int r = 0; r < 4; r++) {
                const int gr = bm + wm + mf * 16 + orow + r;
                float v = acc[mf][nf][r] + b;
                if (ACT == 1) v = fmaxf(v, 0.f);
                Cv[(size_t)gr * ldc + gc] = (_Float16)v;
            }
        }
    }
}

// ---------------------------------------------------------------------------
// tail: h2 = relu(h1 @ w2t + b2), out = h2 . w3 + b3 — fused; BK=64.
// ---------------------------------------------------------------------------
__global__ __launch_bounds__(256)
void tail_k(const _Float16* __restrict__ h1, const _Float16* __restrict__ w2t,
            const float* __restrict__ b2, const float* __restrict__ w3,
            const float* __restrict__ b3, float* __restrict__ out)
{
    __shared__ _Float16 Ash[64][72];
    __shared__ _Float16 Bsh[128][72];
    __shared__ float red[64][2];
    const int tid  = threadIdx.x;
    const int lane = tid & 63;
    const int w    = tid >> 6;
    const int wm   = (w >> 1) * 32;
    const int wn   = (w & 1) * 64;
    const int bm   = blockIdx.x * 64;

    const int fr = lane & 15;
    const int fk = (lane >> 4) * 8;
    const int sr = tid >> 2;
    const int sc = (tid & 3) * 16;

    f32x4 acc[2][4] = {};

    for (int k0 = 0; k0 < 256; k0 += 64) {
        #pragma unroll
        for (int hh = 0; hh < 2; hh++) {
            const int c = sc + hh * 8;
            *reinterpret_cast<half8*>(&Ash[sr][c]) =
                *reinterpret_cast<const half8*>(h1 + (size_t)(bm + sr) * 256 + k0 + c);
            *reinterpret_cast<half8*>(&Bsh[sr][c]) =
                *reinterpret_cast<const half8*>(w2t + (size_t)sr * 256 + k0 + c);
            *reinterpret_cast<half8*>(&Bsh[sr + 64][c]) =
                *reinterpret_cast<const half8*>(w2t + (size_t)(sr + 64) * 256 + k0 + c);
        }
        __syncthreads();

        #pragma unroll
        for (int kk = 0; kk < 64; kk += 32) {
            half8 af[2], bf[4];
            #pragma unroll
            for (int mf = 0; mf < 2; mf++)
                af[mf] = *reinterpret_cast<const half8*>(&Ash[wm + mf * 16 + fr][kk + fk]);
            #pragma unroll
            for (int nf = 0; nf < 4; nf++)
                bf[nf] = *reinterpret_cast<const half8*>(&Bsh[wn + nf * 16 + fr][kk + fk]);
            #pragma unroll
            for (int mf = 0; mf < 2; mf++)
                #pragma unroll
                for (int nf = 0; nf < 4; nf++)
                    acc[mf][nf] = __builtin_amdgcn_mfma_f32_16x16x32_f16(
                        af[mf], bf[nf], acc[mf][nf], 0, 0, 0);
        }
        __syncthreads();
    }

    const int orow = (lane >> 4) * 4;
    const int ocol = lane & 15;
    float part[2][4];
    #pragma unroll
    for (int mf = 0; mf < 2; mf++) {
        #pragma unroll
        for (int r = 0; r < 4; r++) {
            float s = 0.f;
            #pragma unroll
            for (int nf = 0; nf < 4; nf++) {
                const int gc = wn + nf * 16 + ocol;
                float v = acc[mf][nf][r] + b2[gc];
                v = fmaxf(v, 0.f);
                s += v * w3[gc];
            }
            part[mf][r] = s;
        }
    }
    #pragma unroll
    for (int m = 1; m < 16; m <<= 1) {
        #pragma unroll
        for (int mf = 0; mf < 2; mf++)
            #pragma unroll
            for (int r = 0; r < 4; r++)
                part[mf][r] += __shfl_xor(part[mf][r], m);
    }
    if (ocol == 0) {
        #pragma unroll
        for (int mf = 0; mf < 2; mf++)
            #pragma unroll
            for (int r = 0; r < 4; r++)
                red[wm + mf * 16 + orow + r][w & 1] = part[mf][r];
    }
    __syncthreads();
    if (tid < 64)
        out[bm + tid] = red[tid][0] + red[tid][1] + b3[0];
}

// ---------------------------------------------------------------------------
// x_proj MFMA kernel, BK=64: xs (M,512) fp16 -> split x_dbl outputs (fp32).
// ---------------------------------------------------------------------------
__global__ __launch_bounds__(256)
void xproj_k(const _Float16* __restrict__ xs,
             const float* __restrict__ xpw,
             float* __restrict__ dtr32,
             float* __restrict__ xdbl32)
{
    __shared__ _Float16 Ash[64][72];
    __shared__ _Float16 Bsh[48][72];
    const int tid  = threadIdx.x;
    const int lane = tid & 63;
    const int w    = tid >> 6;
    const int bm   = blockIdx.x * 64;
    const int fr   = lane & 15;
    const int fk   = (lane >> 4) * 8;
    const int sr   = tid >> 2;
    const int sc   = (tid & 3) * 16;

    f32x4 acc[3] = {};

    for (int k0 = 0; k0 < 512; k0 += 64) {
        #pragma unroll
        for (int hh = 0; hh < 2; hh++) {
            const int c = sc + hh * 8;
            *reinterpret_cast<half8*>(&Ash[sr][c]) =
                *reinterpret_cast<const half8*>(xs + (size_t)(bm + sr) * 512 + k0 + c);
            if (sr < 48)
                *reinterpret_cast<half8*>(&Bsh[sr][c]) =
                    load_h8<true>(xpw, (size_t)sr * 512 + k0 + c);
        }
        __syncthreads();
        #pragma unroll
        for (int kk = 0; kk < 64; kk += 32) {
            const half8 af = *reinterpret_cast<const half8*>(&Ash[w * 16 + fr][kk + fk]);
            #pragma unroll
            for (int nf = 0; nf < 3; nf++) {
                const half8 bf = *reinterpret_cast<const half8*>(&Bsh[nf * 16 + fr][kk + fk]);
                acc[nf] = __builtin_amdgcn_mfma_f32_16x16x32_f16(af, bf, acc[nf], 0, 0, 0);
            }
        }
        __syncthreads();
    }

    const int orow = (lane >> 4) * 4;
    const int ocol = lane & 15;
    #pragma unroll
    for (int nf = 0; nf < 3; nf++) {
        #pragma unroll
        for (int r = 0; r < 4; r++) {
            const int gr = bm + w * 16 + orow + r;
            const float v = acc[nf][r];
            if (nf == 0)
                dtr32[(size_t)gr * 16 + ocol] = v;
            else
                xdbl32[(size_t)gr * 32 + (nf - 1) * 16 + ocol] = v;
        }
    }
}

// ---------------------------------------------------------------------------
// A-structure check: Av[n] ~= (n+1)*Av[0]
// ---------------------------------------------------------------------------
__device__ __forceinline__ bool a_is_arange(const float* Av)
{
    bool fast = true;
    #pragma unroll
    for (int n = 1; n < DS_; n++)
        fast = fast && (fabsf(Av[n] - (n + 1) * Av[0]) <= 1e-3f * (n + 1));
    return fast;
}

// ---------------------------------------------------------------------------
// softplus(dtr . wreg + bd) from block-uniform dtr row (s_load path)
// ---------------------------------------------------------------------------
__device__ __forceinline__ float dt_inline(const float* __restrict__ dr,
                                           const float* wreg, float bd)
{
    float v = bd;
    #pragma unroll
    for (int r = 0; r < DTR_; r++) v += dr[r] * wreg[r];
    return (v > 20.f) ? v : __logf(1.f + __expf(v));
}

// ---------------------------------------------------------------------------
// Scan phase 1: dt inline (fp32), fast path 1 exp/step; unroll 4.
// ---------------------------------------------------------------------------
__global__ __launch_bounds__(512)
void scan_phase1(const float* __restrict__ dtr32, const float* __restrict__ dtw,
                 const float* __restrict__ dtb, const _Float16* __restrict__ xs,
                 const float* __restrict__ xdbl32, const float* __restrict__ A_log,
                 _Float16* __restrict__ h_end, float* __restrict__ dtsum)
{
    const int c = blockIdx.x, b = blockIdx.y, d = threadIdx.x;
    float Av[DS_], wreg[DTR_];
    #pragma unroll
    for (int n = 0; n < DS_; n++) Av[n] = -expf(A_log[d * DS_ + n]);
    #pragma unroll
    for (int r = 0; r < DTR_; r++) wreg[r] = dtw[d * DTR_ + r];
    const float bd = dtb[d];
    float h[DS_] = {};
    float dts = 0.f;
    const int base = b * L_ + c * CH;
    const size_t rbase = (size_t)base * DI_ + d;
    if (a_is_arange(Av)) {
        const float Av0 = Av[0];
        #pragma unroll 4
        for (int tl = 0; tl < CH; tl++) {
            const float* dr = dtr32 + (size_t)(base + tl) * 16;    // s_load
            const float* Br = xdbl32 + (size_t)(base + tl) * 32;   // s_load
            const float dtv = dt_inline(dr, wreg, bd);
            const float xv  = (float)xs[rbase + (size_t)tl * DI_];
            dts += dtv;
            const float dtx = dtv * xv;
            const float e1 = __expf(dtv * Av0);
            float e = 1.f;
            #pragma unroll
            for (int n = 0; n < DS_; n++) {
                e *= e1;
                h[n] = e * h[n] + dtx * Br[n];
            }
        }
    } else {
        #pragma unroll 4
        for (int tl = 0; tl < CH; tl++) {
            const float* dr = dtr32 + (size_t)(base + tl) * 16;
            const float* Br = xdbl32 + (size_t)(base + tl) * 32;
            const float dtv = dt_inline(dr, wreg, bd);
            const float xv  = (float)xs[rbase + (size_t)tl * DI_];
            dts += dtv;
            const float dtx = dtv * xv;
            #pragma unroll
            for (int n = 0; n < DS_; n++)
                h[n] = __expf(dtv * Av[n]) * h[n] + dtx * Br[n];
        }
    }
    const size_t o = (size_t)(b * NCH + c) * DI_ + d;
    half8 v0, v1;
    #pragma unroll
    for (int n = 0; n < 8; n++) { v0[n] = (_Float16)h[n]; v1[n] = (_Float16)h[8 + n]; }
    half8* he = (half8*)(h_end + o * DS_);
    he[0] = v0; he[1] = v1;
    dtsum[o] = dts;
}

// ---------------------------------------------------------------------------
// Scan phase 2: sequential combine across chunks; unroll 16.
// ---------------------------------------------------------------------------
__global__ __launch_bounds__(256)
void scan_phase2(const _Float16* __restrict__ h_end, const float* __restrict__ dtsum,
                 const float* __restrict__ A_log, _Float16* __restrict__ h_start)
{
    const int gid = blockIdx.x * 256 + threadIdx.x;   // B*DI*DS = 65536
    const int n = gid & 15;
    const int d = (gid >> 4) & (DI_ - 1);
    const int b = gid >> 13;
    const float Av = -expf(A_log[d * DS_ + n]);
    float hs = 0.f;
    #pragma unroll 16
    for (int c = 0; c < NCH; c++) {
        const size_t o = (size_t)(b * NCH + c) * DI_ + d;
        const float e  = __expf(Av * dtsum[o]);
        const float he = (float)h_end[o * DS_ + n];
        h_start[o * DS_ + n] = (_Float16)hs;
        hs = e * hs + he;
    }
}

// ---------------------------------------------------------------------------
// Scan phase 3: dt inline (fp32), replay + gate + y out; fast path; unroll 4.
// ---------------------------------------------------------------------------
__global__ __launch_bounds__(512)
void scan_phase3(const float* __restrict__ dtr32, const float* __restrict__ dtw,
                 const float* __restrict__ dtb, const _Float16* __restrict__ xs,
                 const float* __restrict__ xdbl32, const float* __restrict__ A_log,
                 const float* __restrict__ Dv, const _Float16* __restrict__ gbuf,
                 const _Float16* __restrict__ h_start, _Float16* __restrict__ yout)
{
    const int c = blockIdx.x, b = blockIdx.y, d = threadIdx.x;
    float Av[DS_], wreg[DTR_];
    #pragma unroll
    for (int n = 0; n < DS_; n++) Av[n] = -expf(A_log[d * DS_ + n]);
    #pragma unroll
    for (int r = 0; r < DTR_; r++) wreg[r] = dtw[d * DTR_ + r];
    const float bd = dtb[d];
    float h[DS_];
    {
        const half8* hsv = (const half8*)(h_start + ((size_t)(b * NCH + c) * DI_ + d) * DS_);
        const half8 a = hsv[0], bb = hsv[1];
        #pragma unroll
        for (int n = 0; n < 8; n++) { h[n] = (float)a[n]; h[8 + n] = (float)bb[n]; }
    }
    const float Dd = Dv[d];
    const int base = b * L_ + c * CH;
    const size_t rbase = (size_t)base * DI_ + d;
    if (a_is_arange(Av)) {
        const float Av0 = Av[0];
        #pragma unroll 4
        for (int tl = 0; tl < CH; tl++) {
            const float* dr = dtr32 + (size_t)(base + tl) * 16;    // s_load
            const float* Br = xdbl32 + (size_t)(base + tl) * 32;   // s_load
            const size_t off = rbase + (size_t)tl * DI_;
            const float dtv = dt_inline(dr, wreg, bd);
            const float xv  = (float)xs[off];
            const float g   = (float)gbuf[off];
            const float dtx = dtv * xv;
            const float e1 = __expf(dtv * Av0);
            float e = 1.f;
            float acc = 0.f;
            #pragma unroll
            for (int n = 0; n < DS_; n++) {
                e *= e1;
                h[n] = e * h[n] + dtx * Br[n];
                acc += h[n] * Br[16 + n];
            }
            const float yv = acc + xv * Dd;
            yout[off] = (_Float16)(yv * g);
        }
    } else {
        #pragma unroll 4
        for (int tl = 0; tl < CH; tl++) {
            const float* dr = dtr32 + (size_t)(base + tl) * 16;
            const float* Br = xdbl32 + (size_t)(base + tl) * 32;
            const size_t off = rbase + (size_t)tl * DI_;
            const float dtv = dt_inline(dr, wreg, bd);
            const float xv  = (float)xs[off];
            const float g   = (float)gbuf[off];
            const float dtx = dtv * xv;
            float acc = 0.f;
            #pragma unroll
            for (int n = 0; n < DS_; n++) {
                h[n] = __expf(dtv * Av[n]) * h[n] + dtx * Br[n];
                acc += h[n] * Br[16 + n];
            }
            const float yv = acc + xv * Dd;
            yout[off] = (_Float16)(yv * g);
        }
    }
}

// ---------------------------------------------------------------------------
extern "C" void kernel_launch(void* const* d_in, const int* in_sizes, int n_in,
                              void* d_out, int out_size, void* d_ws, size_t ws_size,
                              hipStream_t stream)
{
    const float* state      = (const float*)d_in[0];
    const float* in_proj_w  = (const float*)d_in[1];
    const float* conv_w     = (const float*)d_in[2];
    const float* conv_b     = (const float*)d_in[3];
    const float* x_proj_w   = (const float*)d_in[4];
    const float* dt_proj_w  = (const float*)d_in[5];
    const float* dt_proj_b  = (const float*)d_in[6];
    const float* A_log      = (const float*)d_in[7];
    const float* Dp         = (const float*)d_in[8];
    const float* out_proj_w = (const float*)d_in[9];
    const float* w1 = (const float*)d_in[10];
    const float* b1 = (const float*)d_in[11];
    const float* w2 = (const float*)d_in[12];
    const float* b2 = (const float*)d_in[13];
    const float* w3 = (const float*)d_in[14];
    const float* b3 = (const float*)d_in[15];

    float* ws = (float*)d_ws;
    float*    xdbl32 = ws;                        //   262,144 f
    float*    dtr32  = xdbl32 + 262144;           //   131,072 f
    float*    dtsum  = dtr32 + 131072;            //   262,144 f
    _Float16* st_h   = (_Float16*)(dtsum + 262144); // 2,097,152 h
    _Float16* wih    = st_h + 2097152;            //   262,144 h
    _Float16* woh    = wih + 262144;              //   131,072 h
    _Float16* gbuf   = woh + 131072;              // 4,194,304 h (silu(z))
    _Float16* xs_h   = gbuf + 4194304;            // 4,194,304 h
    _Float16* he_h   = xs_h + 4194304;            // 4,194,304 h
    _Float16* hs_h   = he_h + 4194304;            // 4,194,304 h
    _Float16* y_h    = hs_h + 4194304;            // 4,194,304 h
    _Float16* outb_h = y_h + 4194304;             // 2,097,152 h
    _Float16* h1_h   = outb_h + 2097152;          // 2,097,152 h
    _Float16* w1t    = h1_h + 2097152;            //    65,536 h
    _Float16* w2t    = w1t + 65536;               //    32,768 h

    // 0. all fp32->fp16 prep in one kernel
    prep_k<<<dim3(2816), 256, 0, stream>>>(
        state, in_proj_w, out_proj_w, w1, w2, st_h, wih, woh, w1t, w2t);

    // 1. in_proj + fused conv/silu (x side) and silu (z side)
    inproj_k<<<dim3(M_/128, 1024/64), 256, 0, stream>>>(
        st_h, wih, conv_w, conv_b, xs_h, gbuf);
    // 2. x_dbl: MFMA fp16 (BK=64), split outputs (dtr32 / xdbl32)
    xproj_k<<<dim3(M_/64), 256, 0, stream>>>(xs_h, x_proj_w, dtr32, xdbl32);
    // 3-5. chunked selective scan (dt inline fp32, 1-exp fast path)
    scan_phase1<<<dim3(NCH, B_), 512, 0, stream>>>(
        dtr32, dt_proj_w, dt_proj_b, xs_h, xdbl32, A_log, he_h, dtsum);
    scan_phase2<<<dim3(256), 256, 0, stream>>>(he_h, dtsum, A_log, hs_h);
    scan_phase3<<<dim3(NCH, B_), 512, 0, stream>>>(
        dtr32, dt_proj_w, dt_proj_b, xs_h, xdbl32, A_log, Dp, gbuf, hs_h, y_h);
    // 6. out = y @ out_proj_w^T  (N=256, K=512) -> fp16
    hgemm64_k<0, false><<<dim3(M_/64, 256/64), 256, 0, stream>>>(
        y_h, DI_, woh, nullptr, outb_h, DM_, DI_);
    // 7. h1 = relu(out @ w1 + b1)  (N=256, K=256) -> fp16
    hgemm64_k<1, true><<<dim3(M_/64, 256/64), 256, 0, stream>>>(
        outb_h, DM_, w1t, b1, h1_h, 256, 256);
    // 8. fused: h2 = relu(h1 @ w2 + b2); out = h2 . w3 + b3
    tail_k<<<dim3(M_/64), 256, 0, stream>>>(h1_h, w2t, b2, w3, b3, (float*)d_out);
}

// Round 22
// 101.643 us; speedup vs baseline: 1.1793x; 1.1793x over previous
//
#include <hip/hip_runtime.h>
#include <cstdint>
#include <cmath>

#define B_   8
#define L_   1024
#define DM_  256
#define DS_  16
#define DC_  4
#define DI_  512
#define DTR_ 16
#define M_   (B_*L_)    // 8192
#define NCH  64         // number of scan chunks
#define CH   16         // chunk length (NCH*CH == L_)

using half8 = __attribute__((ext_vector_type(8))) _Float16;
using half4 = __attribute__((ext_vector_type(4))) _Float16;
using f32x4 = __attribute__((ext_vector_type(4))) float;

// ---------------------------------------------------------------------------
// load 8 contiguous elements as fp16, converting from fp32 if F32
// ---------------------------------------------------------------------------
template<bool F32>
__device__ __forceinline__ half8 load_h8(const void* base, size_t off)
{
    if constexpr (F32) {
        const float* p = (const float*)base + off;
        const float4 a = *reinterpret_cast<const float4*>(p);
        const float4 b = *reinterpret_cast<const float4*>(p + 4);
        half8 h;
        h[0] = (_Float16)a.x; h[1] = (_Float16)a.y;
        h[2] = (_Float16)a.z; h[3] = (_Float16)a.w;
        h[4] = (_Float16)b.x; h[5] = (_Float16)b.y;
        h[6] = (_Float16)b.z; h[7] = (_Float16)b.w;
        return h;
    } else {
        return *reinterpret_cast<const half8*>((const _Float16*)base + off);
    }
}

// ---------------------------------------------------------------------------
// prep: all fp32->fp16 converts in ONE kernel.
// ---------------------------------------------------------------------------
__global__ __launch_bounds__(256)
void prep_k(const float* __restrict__ state, const float* __restrict__ ipw,
            const float* __restrict__ opw,
            const float* __restrict__ w1, const float* __restrict__ w2,
            _Float16* __restrict__ st_h, _Float16* __restrict__ wih,
            _Float16* __restrict__ woh,
            _Float16* __restrict__ w1t, _Float16* __restrict__ w2t)
{
    const int g = blockIdx.x * 256 + threadIdx.x;
    const int N0 = M_ * DM_ / 4;            // 524288
    const int N1 = N0 + 2 * DI_ * DM_ / 4;  // +65536
    const int N2 = N1 + DM_ * DI_ / 4;      // +32768
    const int N3 = N2 + 256 * 256;          // +65536 (scalar)
    const int N4 = N3 + 256 * 128;          // +32768 (scalar)
    if (g < N0) {
        const float4 v = reinterpret_cast<const float4*>(state)[g];
        half4 h; h[0]=(_Float16)v.x; h[1]=(_Float16)v.y; h[2]=(_Float16)v.z; h[3]=(_Float16)v.w;
        reinterpret_cast<half4*>(st_h)[g] = h;
    } else if (g < N1) {
        const int gg = g - N0;
        const float4 v = reinterpret_cast<const float4*>(ipw)[gg];
        half4 h; h[0]=(_Float16)v.x; h[1]=(_Float16)v.y; h[2]=(_Float16)v.z; h[3]=(_Float16)v.w;
        reinterpret_cast<half4*>(wih)[gg] = h;
    } else if (g < N2) {
        const int gg = g - N1;
        const float4 v = reinterpret_cast<const float4*>(opw)[gg];
        half4 h; h[0]=(_Float16)v.x; h[1]=(_Float16)v.y; h[2]=(_Float16)v.z; h[3]=(_Float16)v.w;
        reinterpret_cast<half4*>(woh)[gg] = h;
    } else if (g < N3) {
        const int gg = g - N2;
        const int r = gg >> 8, c = gg & 255;
        w1t[(size_t)c * 256 + r] = (_Float16)w1[gg];
    } else if (g < N4) {
        const int gg = g - N3;
        const int r = gg >> 7, c = gg & 127;
        w2t[(size_t)c * 256 + r] = (_Float16)w2[gg];
    }
}

// ---------------------------------------------------------------------------
// in_proj GEMM + fused causal conv/SiLU on the x side (R15, unchanged).
// ---------------------------------------------------------------------------
__global__ __launch_bounds__(256)
void inproj_k(const _Float16* __restrict__ A, const _Float16* __restrict__ W,
              const float* __restrict__ cw, const float* __restrict__ cb,
              _Float16* __restrict__ xs, _Float16* __restrict__ gout)
{
    __shared__ _Float16 Ash[144][72];
    __shared__ _Float16 Bsh[64][72];
    _Float16 (*xsh)[152] = reinterpret_cast<_Float16(*)[152]>(&Ash[0][0]);

    const int tid  = threadIdx.x;
    const int lane = tid & 63;
    const int w    = tid >> 6;
    const int wm   = (w >> 1) * 64;
    const int wn   = (w & 1) * 32;
    const int bm   = blockIdx.x * 128;
    const int bn   = blockIdx.y * 64;
    const bool xside = (bn < DI_);
    const bool first = ((bm & (L_ - 1)) == 0);

    const int fr = lane & 15;
    const int fk = (lane >> 4) * 8;
    const int sr = tid >> 2;
    const int sc = (tid & 3) * 16;

    f32x4 acc[4][2] = {};
    f32x4 hacc[2] = {};

    for (int k0 = 0; k0 < DM_; k0 += 64) {
        #pragma unroll
        for (int hh = 0; hh < 2; hh++) {
            const int c = sc + hh * 8;
            *reinterpret_cast<half8*>(&Ash[16 + sr][c]) =
                *reinterpret_cast<const half8*>(A + (size_t)(bm + sr) * DM_ + k0 + c);
            *reinterpret_cast<half8*>(&Ash[16 + sr + 64][c]) =
                *reinterpret_cast<const half8*>(A + (size_t)(bm + sr + 64) * DM_ + k0 + c);
            *reinterpret_cast<half8*>(&Bsh[sr][c]) =
                *reinterpret_cast<const half8*>(W + (size_t)(bn + sr) * DM_ + k0 + c);
            if (tid < 64) {
                half8 hv = half8{};
                if (xside && !first)
                    hv = *reinterpret_cast<const half8*>(
                        A + (size_t)(bm - 16 + sr) * DM_ + k0 + c);
                *reinterpret_cast<half8*>(&Ash[sr][c]) = hv;
            }
        }
        __syncthreads();

        #pragma unroll
        for (int kk = 0; kk < 64; kk += 32) {
            half8 af[4], bf[2];
            #pragma unroll
            for (int mf = 0; mf < 4; mf++)
                af[mf] = *reinterpret_cast<const half8*>(&Ash[16 + wm + mf * 16 + fr][kk + fk]);
            #pragma unroll
            for (int nf = 0; nf < 2; nf++)
                bf[nf] = *reinterpret_cast<const half8*>(&Bsh[wn + nf * 16 + fr][kk + fk]);
            #pragma unroll
            for (int mf = 0; mf < 4; mf++)
                #pragma unroll
                for (int nf = 0; nf < 2; nf++)
                    acc[mf][nf] = __builtin_amdgcn_mfma_f32_16x16x32_f16(
                        af[mf], bf[nf], acc[mf][nf], 0, 0, 0);
            if (xside && w < 2) {
                const half8 ha = *reinterpret_cast<const half8*>(&Ash[fr][kk + fk]);
                #pragma unroll
                for (int nf = 0; nf < 2; nf++)
                    hacc[nf] = __builtin_amdgcn_mfma_f32_16x16x32_f16(
                        ha, bf[nf], hacc[nf], 0, 0, 0);
            }
        }
        __syncthreads();
    }

    const int orow = (lane >> 4) * 4;
    const int ocol = lane & 15;

    if (!xside) {
        #pragma unroll
        for (int mf = 0; mf < 4; mf++) {
            #pragma unroll
            for (int nf = 0; nf < 2; nf++) {
                const int gc = bn + wn + nf * 16 + ocol - DI_;
                #pragma unroll
                for (int r = 0; r < 4; r++) {
                    const int gr = bm + wm + mf * 16 + orow + r;
                    const float v = acc[mf][nf][r];
                    const float g = v * (1.f / (1.f + __expf(-v)));
                    gout[(size_t)gr * DI_ + gc] = (_Float16)g;
                }
            }
        }
        return;
    }

    #pragma unroll
    for (int mf = 0; mf < 4; mf++) {
        #pragma unroll
        for (int nf = 0; nf < 2; nf++) {
            half4 hv;
            #pragma unroll
            for (int r = 0; r < 4; r++) hv[r] = (_Float16)acc[mf][nf][r];
            *reinterpret_cast<half4*>(
                &xsh[wn + nf * 16 + ocol][16 + wm + mf * 16 + orow]) = hv;
        }
    }
    if (w < 2) {
        #pragma unroll
        for (int nf = 0; nf < 2; nf++) {
            half4 hv;
            #pragma unroll
            for (int r = 0; r < 4; r++) hv[r] = (_Float16)hacc[nf][r];
            *reinterpret_cast<half4*>(&xsh[wn + nf * 16 + ocol][orow]) = hv;
        }
    }
    __syncthreads();

    const int cc = tid & 63;
    const int r0 = (tid >> 6) * 32;
    const int gc = bn + cc;
    const float cb0 = cb[gc];
    float cwv[DC_];
    #pragma unroll
    for (int k = 0; k < DC_; k++) cwv[k] = cw[gc * DC_ + k];

    float xw[36];
    #pragma unroll
    for (int q = 0; q < 9; q++) {
        const half4 hv = *reinterpret_cast<const half4*>(&xsh[cc][12 + r0 + 4 * q]);
        #pragma unroll
        for (int j = 0; j < 4; j++) xw[4 * q + j] = (float)hv[j];
    }
    #pragma unroll
    for (int i = 0; i < 32; i++) {
        float a = cb0;
        #pragma unroll
        for (int k = 0; k < DC_; k++)
            a += xw[1 + i + k] * cwv[k];
        const float s = a * (1.f / (1.f + __expf(-a)));
        xs[(size_t)(bm + r0 + i) * DI_ + gc] = (_Float16)s;
    }
}

// ---------------------------------------------------------------------------
// fp16 MFMA GEMM, tile 64x64, BK=64 (out_proj, mlp1).
// ---------------------------------------------------------------------------
template<int ACT, bool BIAS>
__global__ __launch_bounds__(256)
void hgemm64_k(const _Float16* __restrict__ A, int lda,
               const _Float16* __restrict__ W,
               const float* __restrict__ bias,
               _Float16* __restrict__ Cv, int ldc, int K)
{
    __shared__ _Float16 Ash[64][72];
    __shared__ _Float16 Bsh[64][72];
    const int tid  = threadIdx.x;
    const int lane = tid & 63;
    const int w    = tid >> 6;
    const int wm   = (w >> 1) * 32;
    const int wn   = (w & 1) * 32;
    const int bm   = blockIdx.x * 64;
    const int bn   = blockIdx.y * 64;

    const int fr = lane & 15;
    const int fk = (lane >> 4) * 8;
    const int sr = tid >> 2;
    const int sc = (tid & 3) * 16;

    f32x4 acc[2][2] = {};

    for (int k0 = 0; k0 < K; k0 += 64) {
        #pragma unroll
        for (int hh = 0; hh < 2; hh++) {
            const int c = sc + hh * 8;
            *reinterpret_cast<half8*>(&Ash[sr][c]) =
                *reinterpret_cast<const half8*>(A + (size_t)(bm + sr) * lda + k0 + c);
            *reinterpret_cast<half8*>(&Bsh[sr][c]) =
                *reinterpret_cast<const half8*>(W + (size_t)(bn + sr) * K + k0 + c);
        }
        __syncthreads();

        #pragma unroll
        for (int kk = 0; kk < 64; kk += 32) {
            half8 af[2], bf[2];
            #pragma unroll
            for (int mf = 0; mf < 2; mf++)
                af[mf] = *reinterpret_cast<const half8*>(&Ash[wm + mf * 16 + fr][kk + fk]);
            #pragma unroll
            for (int nf = 0; nf < 2; nf++)
                bf[nf] = *reinterpret_cast<const half8*>(&Bsh[wn + nf * 16 + fr][kk + fk]);
            #pragma unroll
            for (int mf = 0; mf < 2; mf++)
                #pragma unroll
                for (int nf = 0; nf < 2; nf++)
                    acc[mf][nf] = __builtin_amdgcn_mfma_f32_16x16x32_f16(
                        af[mf], bf[nf], acc[mf][nf], 0, 0, 0);
        }
        __syncthreads();
    }

    const int orow = (lane >> 4) * 4;
    const int ocol = lane & 15;
    #pragma unroll
    for (int mf = 0; mf < 2; mf++) {
        #pragma unroll
        for (int nf = 0; nf < 2; nf++) {
            const int gc = bn + wn + nf * 16 + ocol;
            float b = BIAS ? bias[gc] : 0.f;
            #pragma unroll
            for (int r = 0; r < 4; r++) {
                const int gr = bm + wm + mf * 16 + orow + r;
                float v = acc[mf][nf][r] + b;
                if (ACT == 1) v = fmaxf(v, 0.f);
                Cv[(size_t)gr * ldc + gc] = (_Float16)v;
            }
        }
    }
}

// ---------------------------------------------------------------------------
// tail: h2 = relu(h1 @ w2t + b2), out = h2 . w3 + b3 — fused; BK=64.
// ---------------------------------------------------------------------------
__global__ __launch_bounds__(256)
void tail_k(const _Float16* __restrict__ h1, const _Float16* __restrict__ w2t,
            const float* __restrict__ b2, const float* __restrict__ w3,
            const float* __restrict__ b3, float* __restrict__ out)
{
    __shared__ _Float16 Ash[64][72];
    __shared__ _Float16 Bsh[128][72];
    __shared__ float red[64][2];
    const int tid  = threadIdx.x;
    const int lane = tid & 63;
    const int w    = tid >> 6;
    const int wm   = (w >> 1) * 32;
    const int wn   = (w & 1) * 64;
    const int bm   = blockIdx.x * 64;

    const int fr = lane & 15;
    const int fk = (lane >> 4) * 8;
    const int sr = tid >> 2;
    const int sc = (tid & 3) * 16;

    f32x4 acc[2][4] = {};

    for (int k0 = 0; k0 < 256; k0 += 64) {
        #pragma unroll
        for (int hh = 0; hh < 2; hh++) {
            const int c = sc + hh * 8;
            *reinterpret_cast<half8*>(&Ash[sr][c]) =
                *reinterpret_cast<const half8*>(h1 + (size_t)(bm + sr) * 256 + k0 + c);
            *reinterpret_cast<half8*>(&Bsh[sr][c]) =
                *reinterpret_cast<const half8*>(w2t + (size_t)sr * 256 + k0 + c);
            *reinterpret_cast<half8*>(&Bsh[sr + 64][c]) =
                *reinterpret_cast<const half8*>(w2t + (size_t)(sr + 64) * 256 + k0 + c);
        }
        __syncthreads();

        #pragma unroll
        for (int kk = 0; kk < 64; kk += 32) {
            half8 af[2], bf[4];
            #pragma unroll
            for (int mf = 0; mf < 2; mf++)
                af[mf] = *reinterpret_cast<const half8*>(&Ash[wm + mf * 16 + fr][kk + fk]);
            #pragma unroll
            for (int nf = 0; nf < 4; nf++)
                bf[nf] = *reinterpret_cast<const half8*>(&Bsh[wn + nf * 16 + fr][kk + fk]);
            #pragma unroll
            for (int mf = 0; mf < 2; mf++)
                #pragma unroll
                for (int nf = 0; nf < 4; nf++)
                    acc[mf][nf] = __builtin_amdgcn_mfma_f32_16x16x32_f16(
                        af[mf], bf[nf], acc[mf][nf], 0, 0, 0);
        }
        __syncthreads();
    }

    const int orow = (lane >> 4) * 4;
    const int ocol = lane & 15;
    float part[2][4];
    #pragma unroll
    for (int mf = 0; mf < 2; mf++) {
        #pragma unroll
        for (int r = 0; r < 4; r++) {
            float s = 0.f;
            #pragma unroll
            for (int nf = 0; nf < 4; nf++) {
                const int gc = wn + nf * 16 + ocol;
                float v = acc[mf][nf][r] + b2[gc];
                v = fmaxf(v, 0.f);
                s += v * w3[gc];
            }
            part[mf][r] = s;
        }
    }
    #pragma unroll
    for (int m = 1; m < 16; m <<= 1) {
        #pragma unroll
        for (int mf = 0; mf < 2; mf++)
            #pragma unroll
            for (int r = 0; r < 4; r++)
                part[mf][r] += __shfl_xor(part[mf][r], m);
    }
    if (ocol == 0) {
        #pragma unroll
        for (int mf = 0; mf < 2; mf++)
            #pragma unroll
            for (int r = 0; r < 4; r++)
                red[wm + mf * 16 + orow + r][w & 1] = part[mf][r];
    }
    __syncthreads();
    if (tid < 64)
        out[bm + tid] = red[tid][0] + red[tid][1] + b3[0];
}

// ---------------------------------------------------------------------------
// x_proj MFMA kernel: xs (M,512) fp16 -> split x_dbl outputs (fp32).
// ---------------------------------------------------------------------------
__global__ __launch_bounds__(256)
void xproj_k(const _Float16* __restrict__ xs,
             const float* __restrict__ xpw,
             float* __restrict__ dtr32,
             float* __restrict__ xdbl32)
{
    __shared__ _Float16 Ash[64][40];
    __shared__ _Float16 Bsh[48][40];
    const int tid  = threadIdx.x;
    const int lane = tid & 63;
    const int w    = tid >> 6;
    const int bm   = blockIdx.x * 64;
    const int fr   = lane & 15;
    const int fk   = (lane >> 4) * 8;
    const int sr   = tid >> 2;
    const int sg   = (tid & 3) * 8;

    f32x4 acc[3] = {};

    for (int k0 = 0; k0 < 512; k0 += 32) {
        *reinterpret_cast<half8*>(&Ash[sr][sg]) =
            load_h8<false>(xs, (size_t)(bm + sr) * 512 + k0 + sg);
        if (sr < 48)
            *reinterpret_cast<half8*>(&Bsh[sr][sg]) =
                load_h8<true>(xpw, (size_t)sr * 512 + k0 + sg);
        __syncthreads();
        const half8 af = *reinterpret_cast<const half8*>(&Ash[w * 16 + fr][fk]);
        #pragma unroll
        for (int nf = 0; nf < 3; nf++) {
            const half8 bf = *reinterpret_cast<const half8*>(&Bsh[nf * 16 + fr][fk]);
            acc[nf] = __builtin_amdgcn_mfma_f32_16x16x32_f16(af, bf, acc[nf], 0, 0, 0);
        }
        __syncthreads();
    }

    const int orow = (lane >> 4) * 4;
    const int ocol = lane & 15;
    #pragma unroll
    for (int nf = 0; nf < 3; nf++) {
        #pragma unroll
        for (int r = 0; r < 4; r++) {
            const int gr = bm + w * 16 + orow + r;
            const float v = acc[nf][r];
            if (nf == 0)
                dtr32[(size_t)gr * 16 + ocol] = v;
            else
                xdbl32[(size_t)gr * 32 + (nf - 1) * 16 + ocol] = v;
        }
    }
}

// ---------------------------------------------------------------------------
// A-structure check: Av[n] ~= (n+1)*Av[0]
// ---------------------------------------------------------------------------
__device__ __forceinline__ bool a_is_arange(const float* Av)
{
    bool fast = true;
    #pragma unroll
    for (int n = 1; n < DS_; n++)
        fast = fast && (fabsf(Av[n] - (n + 1) * Av[0]) <= 1e-3f * (n + 1));
    return fast;
}

// ---------------------------------------------------------------------------
// softplus(dtr . wreg + bd) from block-uniform dtr row (s_load path)
// ---------------------------------------------------------------------------
__device__ __forceinline__ float dt_inline(const float* __restrict__ dr,
                                           const float* wreg, float bd)
{
    float v = bd;
    #pragma unroll
    for (int r = 0; r < DTR_; r++) v += dr[r] * wreg[r];
    return (v > 20.f) ? v : __logf(1.f + __expf(v));
}

// ---------------------------------------------------------------------------
// Scan phase 1: dt inline (fp32), fast path 1 exp/step; unroll 4.
// ---------------------------------------------------------------------------
__global__ __launch_bounds__(512)
void scan_phase1(const float* __restrict__ dtr32, const float* __restrict__ dtw,
                 const float* __restrict__ dtb, const _Float16* __restrict__ xs,
                 const float* __restrict__ xdbl32, const float* __restrict__ A_log,
                 _Float16* __restrict__ h_end, float* __restrict__ dtsum)
{
    const int c = blockIdx.x, b = blockIdx.y, d = threadIdx.x;
    float Av[DS_], wreg[DTR_];
    #pragma unroll
    for (int n = 0; n < DS_; n++) Av[n] = -expf(A_log[d * DS_ + n]);
    #pragma unroll
    for (int r = 0; r < DTR_; r++) wreg[r] = dtw[d * DTR_ + r];
    const float bd = dtb[d];
    float h[DS_] = {};
    float dts = 0.f;
    const int base = b * L_ + c * CH;
    const size_t rbase = (size_t)base * DI_ + d;
    if (a_is_arange(Av)) {
        const float Av0 = Av[0];
        #pragma unroll 4
        for (int tl = 0; tl < CH; tl++) {
            const float* dr = dtr32 + (size_t)(base + tl) * 16;    // s_load
            const float* Br = xdbl32 + (size_t)(base + tl) * 32;   // s_load
            const float dtv = dt_inline(dr, wreg, bd);
            const float xv  = (float)xs[rbase + (size_t)tl * DI_];
            dts += dtv;
            const float dtx = dtv * xv;
            const float e1 = __expf(dtv * Av0);
            float e = 1.f;
            #pragma unroll
            for (int n = 0; n < DS_; n++) {
                e *= e1;
                h[n] = e * h[n] + dtx * Br[n];
            }
        }
    } else {
        #pragma unroll 4
        for (int tl = 0; tl < CH; tl++) {
            const float* dr = dtr32 + (size_t)(base + tl) * 16;
            const float* Br = xdbl32 + (size_t)(base + tl) * 32;
            const float dtv = dt_inline(dr, wreg, bd);
            const float xv  = (float)xs[rbase + (size_t)tl * DI_];
            dts += dtv;
            const float dtx = dtv * xv;
            #pragma unroll
            for (int n = 0; n < DS_; n++)
                h[n] = __expf(dtv * Av[n]) * h[n] + dtx * Br[n];
        }
    }
    const size_t o = (size_t)(b * NCH + c) * DI_ + d;
    half8 v0, v1;
    #pragma unroll
    for (int n = 0; n < 8; n++) { v0[n] = (_Float16)h[n]; v1[n] = (_Float16)h[8 + n]; }
    half8* he = (half8*)(h_end + o * DS_);
    he[0] = v0; he[1] = v1;
    dtsum[o] = dts;
}

// ---------------------------------------------------------------------------
// Scan phase 2: sequential combine across chunks; unroll 8.
// ---------------------------------------------------------------------------
__global__ __launch_bounds__(256)
void scan_phase2(const _Float16* __restrict__ h_end, const float* __restrict__ dtsum,
                 const float* __restrict__ A_log, _Float16* __restrict__ h_start)
{
    const int gid = blockIdx.x * 256 + threadIdx.x;   // B*DI*DS = 65536
    const int n = gid & 15;
    const int d = (gid >> 4) & (DI_ - 1);
    const int b = gid >> 13;
    const float Av = -expf(A_log[d * DS_ + n]);
    float hs = 0.f;
    #pragma unroll 8
    for (int c = 0; c < NCH; c++) {
        const size_t o = (size_t)(b * NCH + c) * DI_ + d;
        const float e  = __expf(Av * dtsum[o]);
        const float he = (float)h_end[o * DS_ + n];
        h_start[o * DS_ + n] = (_Float16)hs;
        hs = e * hs + he;
    }
}

// ---------------------------------------------------------------------------
// Scan phase 3: dt inline (fp32), replay + gate + y out; fast path; unroll 4.
// ---------------------------------------------------------------------------
__global__ __launch_bounds__(512)
void scan_phase3(const float* __restrict__ dtr32, const float* __restrict__ dtw,
                 const float* __restrict__ dtb, const _Float16* __restrict__ xs,
                 const float* __restrict__ xdbl32, const float* __restrict__ A_log,
                 const float* __restrict__ Dv, const _Float16* __restrict__ gbuf,
                 const _Float16* __restrict__ h_start, _Float16* __restrict__ yout)
{
    const int c = blockIdx.x, b = blockIdx.y, d = threadIdx.x;
    float Av[DS_], wreg[DTR_];
    #pragma unroll
    for (int n = 0; n < DS_; n++) Av[n] = -expf(A_log[d * DS_ + n]);
    #pragma unroll
    for (int r = 0; r < DTR_; r++) wreg[r] = dtw[d * DTR_ + r];
    const float bd = dtb[d];
    float h[DS_];
    {
        const half8* hsv = (const half8*)(h_start + ((size_t)(b * NCH + c) * DI_ + d) * DS_);
        const half8 a = hsv[0], bb = hsv[1];
        #pragma unroll
        for (int n = 0; n < 8; n++) { h[n] = (float)a[n]; h[8 + n] = (float)bb[n]; }
    }
    const float Dd = Dv[d];
    const int base = b * L_ + c * CH;
    const size_t rbase = (size_t)base * DI_ + d;
    if (a_is_arange(Av)) {
        const float Av0 = Av[0];
        #pragma unroll 4
        for (int tl = 0; tl < CH; tl++) {
            const float* dr = dtr32 + (size_t)(base + tl) * 16;    // s_load
            const float* Br = xdbl32 + (size_t)(base + tl) * 32;   // s_load
            const size_t off = rbase + (size_t)tl * DI_;
            const float dtv = dt_inline(dr, wreg, bd);
            const float xv  = (float)xs[off];
            const float g   = (float)gbuf[off];
            const float dtx = dtv * xv;
            const float e1 = __expf(dtv * Av0);
            float e = 1.f;
            float acc = 0.f;
            #pragma unroll
            for (int n = 0; n < DS_; n++) {
                e *= e1;
                h[n] = e * h[n] + dtx * Br[n];
                acc += h[n] * Br[16 + n];
            }
            const float yv = acc + xv * Dd;
            yout[off] = (_Float16)(yv * g);
        }
    } else {
        #pragma unroll 4
        for (int tl = 0; tl < CH; tl++) {
            const float* dr = dtr32 + (size_t)(base + tl) * 16;
            const float* Br = xdbl32 + (size_t)(base + tl) * 32;
            const size_t off = rbase + (size_t)tl * DI_;
            const float dtv = dt_inline(dr, wreg, bd);
            const float xv  = (float)xs[off];
            const float g   = (float)gbuf[off];
            const float dtx = dtv * xv;
            float acc = 0.f;
            #pragma unroll
            for (int n = 0; n < DS_; n++) {
                h[n] = __expf(dtv * Av[n]) * h[n] + dtx * Br[n];
                acc += h[n] * Br[16 + n];
            }
            const float yv = acc + xv * Dd;
            yout[off] = (_Float16)(yv * g);
        }
    }
}

// ---------------------------------------------------------------------------
extern "C" void kernel_launch(void* const* d_in, const int* in_sizes, int n_in,
                              void* d_out, int out_size, void* d_ws, size_t ws_size,
                              hipStream_t stream)
{
    const float* state      = (const float*)d_in[0];
    const float* in_proj_w  = (const float*)d_in[1];
    const float* conv_w     = (const float*)d_in[2];
    const float* conv_b     = (const float*)d_in[3];
    const float* x_proj_w   = (const float*)d_in[4];
    const float* dt_proj_w  = (const float*)d_in[5];
    const float* dt_proj_b  = (const float*)d_in[6];
    const float* A_log      = (const float*)d_in[7];
    const float* Dp         = (const float*)d_in[8];
    const float* out_proj_w = (const float*)d_in[9];
    const float* w1 = (const float*)d_in[10];
    const float* b1 = (const float*)d_in[11];
    const float* w2 = (const float*)d_in[12];
    const float* b2 = (const float*)d_in[13];
    const float* w3 = (const float*)d_in[14];
    const float* b3 = (const float*)d_in[15];

    float* ws = (float*)d_ws;
    float*    xdbl32 = ws;                        //   262,144 f
    float*    dtr32  = xdbl32 + 262144;           //   131,072 f
    float*    dtsum  = dtr32 + 131072;            //   262,144 f
    _Float16* st_h   = (_Float16*)(dtsum + 262144); // 2,097,152 h
    _Float16* wih    = st_h + 2097152;            //   262,144 h
    _Float16* woh    = wih + 262144;              //   131,072 h
    _Float16* gbuf   = woh + 131072;              // 4,194,304 h (silu(z))
    _Float16* xs_h   = gbuf + 4194304;            // 4,194,304 h
    _Float16* he_h   = xs_h + 4194304;            // 4,194,304 h
    _Float16* hs_h   = he_h + 4194304;            // 4,194,304 h
    _Float16* y_h    = hs_h + 4194304;            // 4,194,304 h
    _Float16* outb_h = y_h + 4194304;             // 2,097,152 h
    _Float16* h1_h   = outb_h + 2097152;          // 2,097,152 h
    _Float16* w1t    = h1_h + 2097152;            //    65,536 h
    _Float16* w2t    = w1t + 65536;               //    32,768 h

    // 0. all fp32->fp16 prep in one kernel
    prep_k<<<dim3(2816), 256, 0, stream>>>(
        state, in_proj_w, out_proj_w, w1, w2, st_h, wih, woh, w1t, w2t);

    // 1. in_proj + fused conv/silu (x side) and silu (z side)
    inproj_k<<<dim3(M_/128, 1024/64), 256, 0, stream>>>(
        st_h, wih, conv_w, conv_b, xs_h, gbuf);
    // 2. x_dbl: MFMA fp16, split outputs (dtr32 / xdbl32)
    xproj_k<<<dim3(M_/64), 256, 0, stream>>>(xs_h, x_proj_w, dtr32, xdbl32);
    // 3-5. chunked selective scan (dt inline fp32, 1-exp fast path)
    scan_phase1<<<dim3(NCH, B_), 512, 0, stream>>>(
        dtr32, dt_proj_w, dt_proj_b, xs_h, xdbl32, A_log, he_h, dtsum);
    scan_phase2<<<dim3(256), 256, 0, stream>>>(he_h, dtsum, A_log, hs_h);
    scan_phase3<<<dim3(NCH, B_), 512, 0, stream>>>(
        dtr32, dt_proj_w, dt_proj_b, xs_h, xdbl32, A_log, Dp, gbuf, hs_h, y_h);
    // 6. out = y @ out_proj_w^T  (N=256, K=512) -> fp16
    hgemm64_k<0, false><<<dim3(M_/64, 256/64), 256, 0, stream>>>(
        y_h, DI_, woh, nullptr, outb_h, DM_, DI_);
    // 7. h1 = relu(out @ w1 + b1)  (N=256, K=256) -> fp16
    hgemm64_k<1, true><<<dim3(M_/64, 256/64), 256, 0, stream>>>(
        outb_h, DM_, w1t, b1, h1_h, 256, 256);
    // 8. fused: h2 = relu(h1 @ w2 + b2); out = h2 . w3 + b3
    tail_k<<<dim3(M_/64), 256, 0, stream>>>(h1_h, w2t, b2, w3, b3, (float*)d_out);
}